// Round 15
// baseline (371.680 us; speedup 1.0000x reference)
//
#include <hip/hip_runtime.h>

typedef __attribute__((ext_vector_type(4))) float f32x4;
typedef __attribute__((ext_vector_type(8))) short s16x8;

static __device__ __forceinline__ unsigned short f2bf(float f) {
  unsigned int u = __builtin_bit_cast(unsigned int, f);
  u += 0x7fffu + ((u >> 16) & 1u);
  return (unsigned short)(u >> 16);
}
static __device__ __forceinline__ float bf2f(unsigned short u) {
  return __builtin_bit_cast(float, (unsigned int)u << 16);
}
static __device__ __forceinline__ float sigm(float x) { return 1.0f / (1.0f + __expf(-x)); }

// async global->LDS, 16B per lane. LDS dest = wave-uniform base + lane*16.
static __device__ __forceinline__ void gload16(const unsigned short* g, unsigned short* l) {
  __builtin_amdgcn_global_load_lds(
      (const __attribute__((address_space(1))) void*)g,
      (__attribute__((address_space(3))) void*)l, 16, 0, 0);
}

// ---------------- fused rmsnorm(P) + transpose ----------------
// block = (b, mt): 64 rows of P. Phase 1: per-row sumsq (HBM read).
// Phase 2: re-read (L2), normalize*inw -> Pn (row-major) + Pnt (transposed).
__global__ __launch_bounds__(256) void rmstp_k(const float* __restrict__ P,
                                               const float* __restrict__ inw,
                                               unsigned short* __restrict__ Pn,
                                               unsigned short* __restrict__ Pnt) {
  __shared__ float psum[64][4];
  __shared__ float rinv[64];
  __shared__ float winw[1024];
  __shared__ unsigned short tile[64][65];
  const int blk = blockIdx.x;
  const int b = blk >> 6, mt = blk & 63;
  const int tid = threadIdx.x, lane = tid & 63, wid = tid >> 6;
  const float* base = P + ((long)b * 4096 + (long)mt * 64) * 1024;
  {
    float4 w4 = ((const float4*)inw)[tid];
    *(float4*)(&winw[tid * 4]) = w4;
  }
  // phase 1: per-row sumsq
  for (int r = 0; r < 64; r++) {
    float4 v = ((const float4*)(base + (long)r * 1024))[tid];
    float ss = v.x * v.x + v.y * v.y + v.z * v.z + v.w * v.w;
    #pragma unroll
    for (int off = 32; off; off >>= 1) ss += __shfl_xor(ss, off, 64);
    if (lane == 0) psum[r][wid] = ss;
  }
  __syncthreads();
  if (tid < 64) {
    float tot = psum[tid][0] + psum[tid][1] + psum[tid][2] + psum[tid][3];
    rinv[tid] = rsqrtf(tot * (1.0f / 1024.0f) + 1e-6f);
  }
  __syncthreads();
  // phase 2: 16 column-tiles of 64
  const int rr = tid >> 4;         // 0..15
  const int c4 = (tid & 15) * 4;   // 0..60
  for (int dt = 0; dt < 16; dt++) {
    #pragma unroll
    for (int i = 0; i < 4; i++) {
      int r = i * 16 + rr;
      float4 v = *(const float4*)(base + (long)r * 1024 + dt * 64 + c4);
      float rs = rinv[r];
      ushort4 o;
      o.x = f2bf(v.x * rs * winw[dt * 64 + c4]);
      o.y = f2bf(v.y * rs * winw[dt * 64 + c4 + 1]);
      o.z = f2bf(v.z * rs * winw[dt * 64 + c4 + 2]);
      o.w = f2bf(v.w * rs * winw[dt * 64 + c4 + 3]);
      *(ushort4*)(Pn + ((long)b * 4096 + mt * 64 + r) * 1024 + dt * 64 + c4) = o;
      tile[r][c4] = o.x; tile[r][c4 + 1] = o.y; tile[r][c4 + 2] = o.z; tile[r][c4 + 3] = o.w;
    }
    __syncthreads();
    #pragma unroll
    for (int i = 0; i < 4; i++) {
      int c = i * 16 + rr;   // d within tile
      ushort4 o;
      o.x = tile[c4][c]; o.y = tile[c4 + 1][c]; o.z = tile[c4 + 2][c]; o.w = tile[c4 + 3][c];
      *(ushort4*)(Pnt + ((long)b * 1024 + dt * 64 + c) * 4096 + (long)mt * 64 + c4) = o;
    }
    __syncthreads();
  }
}

// ---------------- fp32->bf16 convert chunk ----------------
static __device__ __forceinline__ void cvt_chunk(const float* __restrict__ in,
                                                 unsigned short* __restrict__ out, long i) {
  const float4* p = (const float4*)in;
  float4 a = p[i * 2], b = p[i * 2 + 1];
  ushort4 lo, hi;
  lo.x = f2bf(a.x); lo.y = f2bf(a.y); lo.z = f2bf(a.z); lo.w = f2bf(a.w);
  hi.x = f2bf(b.x); hi.y = f2bf(b.y); hi.z = f2bf(b.z); hi.w = f2bf(b.w);
  ushort4* o = (ushort4*)out;
  o[i * 2] = lo;
  o[i * 2 + 1] = hi;
}

// ---------------- combined prologue prep ----------------
// grid 4352: [0,768)    transpose-cvt Wq/Wk/Wv -> wqt/wkt/wvt (64x64 tiles)
//            [768,3840) cvt wi (1536 blocks) then wh (1536 blocks)
//            [3840,4352) rmsnorm(slots_in) -> sn + raw bf16 -> slotsb
__global__ __launch_bounds__(256) void prep_k(
    const float* __restrict__ Wq, const float* __restrict__ Wk, const float* __restrict__ Wv,
    const float* __restrict__ wi, const float* __restrict__ wh,
    const float* __restrict__ slots_in, const float* __restrict__ snw,
    unsigned short* __restrict__ wqt, unsigned short* __restrict__ wkt,
    unsigned short* __restrict__ wvt, unsigned short* __restrict__ wi_b,
    unsigned short* __restrict__ wh_b, unsigned short* __restrict__ sn,
    unsigned short* __restrict__ slotsb) {
  __shared__ float tile[64][65];
  const int x = blockIdx.x;
  const int tid = threadIdx.x;
  if (x < 768) {
    const int z = x >> 8, t = x & 255;
    const float* in = (z == 0) ? Wq : (z == 1) ? Wk : Wv;
    unsigned short* out = (z == 0) ? wqt : (z == 1) ? wkt : wvt;
    const int r0 = (t >> 4) * 64, c0 = (t & 15) * 64;
    #pragma unroll
    for (int i = 0; i < 4; i++) {
      int idx = tid + i * 256;
      int r = idx >> 4, c4 = (idx & 15) * 4;
      float4 v = *(const float4*)(in + (long)(r0 + r) * 1024 + c0 + c4);
      tile[r][c4] = v.x; tile[r][c4 + 1] = v.y; tile[r][c4 + 2] = v.z; tile[r][c4 + 3] = v.w;
    }
    __syncthreads();
    #pragma unroll
    for (int i = 0; i < 4; i++) {
      int idx = tid + i * 256;
      int c = idx >> 4, r4 = (idx & 15) * 4;
      ushort4 o;
      o.x = f2bf(tile[r4][c]);     o.y = f2bf(tile[r4 + 1][c]);
      o.z = f2bf(tile[r4 + 2][c]); o.w = f2bf(tile[r4 + 3][c]);
      *(ushort4*)(out + (long)(c0 + c) * 1024 + r0 + r4) = o;
    }
  } else if (x < 3840) {
    const int y = x - 768;
    if (y < 1536) cvt_chunk(wi, wi_b, (long)y * 256 + tid);
    else          cvt_chunk(wh, wh_b, (long)(y - 1536) * 256 + tid);
  } else {
    const int row = x - 3840;
    const float4* xp = (const float4*)(slots_in + (long)row * 1024);
    float4 v = xp[tid];
    float ss = v.x * v.x + v.y * v.y + v.z * v.z + v.w * v.w;
    #pragma unroll
    for (int off = 32; off; off >>= 1) ss += __shfl_xor(ss, off, 64);
    float* sb = &tile[0][0];
    if ((tid & 63) == 0) sb[tid >> 6] = ss;
    __syncthreads();
    float tot = sb[0] + sb[1] + sb[2] + sb[3];
    float rs = rsqrtf(tot * (1.0f / 1024.0f) + 1e-6f);
    float4 wv = ((const float4*)snw)[tid];
    ushort4 o;
    o.x = f2bf(v.x * rs * wv.x); o.y = f2bf(v.y * rs * wv.y);
    o.z = f2bf(v.z * rs * wv.z); o.w = f2bf(v.w * rs * wv.w);
    ((ushort4*)sn)[(long)row * 256 + tid] = o;
    ushort4 r;
    r.x = f2bf(v.x); r.y = f2bf(v.y); r.z = f2bf(v.z); r.w = f2bf(v.w);
    ((ushort4*)slotsb)[(long)row * 256 + tid] = r;
  }
}

// ---------------- GEMM: C = alpha * A[M][K] @ W[N][K]^T (+bias) ----------------
// EPI: 0 = plain store; 2 = softmax over M(=64) -> bf16 attn + row partials.
// SPLIT: K-split batching. QGH: z=0 -> A/W cols[0,1024); z>0 -> A2/W2 slab.
// M12: blockIdx.y >= 16 switches W to W2 (combined A/C buffers).
template <int BM, int BN, int WR, int WC, typename CT, int EPI, int SPLIT, int QGH, int M12>
__global__ __launch_bounds__(WR * WC * 64) void gemm_bt(
    const unsigned short* __restrict__ A, const unsigned short* __restrict__ W,
    CT* __restrict__ C, int N, int Klen, int lda, int ldw,
    long sA, long sW, long sC, const float* __restrict__ bias,
    const float* __restrict__ bias2, float alpha, float* __restrict__ rs_part,
    const unsigned short* __restrict__ A2, const unsigned short* __restrict__ W2) {
  constexpr int BK = 64;
  constexpr int NT = WR * WC * 64;
  static_assert(NT == 256, "256 threads");
  constexpr int WSM = BM / WR, WSN = BN / WC;
  constexpr int MR = WSM / 16, NR = WSN / 16;
  constexpr int SEG_A = BM / 8, SEG_W = BN / 8;
  constexpr int PA = SEG_A / 4, PW = SEG_W / 4;
  static_assert(SEG_A % 4 == 0 && SEG_W % 4 == 0, "seg divisibility");
  __shared__ unsigned short As[BM * BK];
  __shared__ unsigned short Ws[BN * BK];
  const int tid = threadIdx.x, lane = tid & 63, wid = tid >> 6;
  const int wr = wid / WC, wc = wid % WC;
  const int tileN = blockIdx.x * BN, tileM = blockIdx.y * BM;
  int coff = 0;
  int zb = 0;
  if constexpr (QGH) {
    const int zz = blockIdx.z;
    if (zz > 0) {
      A = A2;
      W = W2 + (long)(zz - 1) * 1024 * ldw;
      bias = bias2 + (zz - 1) * 1024;
      coff = zz * 1024;
    }
  } else if constexpr (M12) {
    if (blockIdx.y >= 16) W = W2;
  } else {
    zb = blockIdx.z / SPLIT;
    const int zs = blockIdx.z % SPLIT;
    A += (long)zb * sA + (long)zs * Klen;
    W += (long)zb * sW + (long)zs * Klen;
    C += (long)blockIdx.z * sC;
  }
  const int srow = lane >> 3;
  const int scol = (lane & 7) * 8;
  f32x4 acc[MR][NR];
  #pragma unroll
  for (int i = 0; i < MR; i++)
    #pragma unroll
    for (int j = 0; j < NR; j++) acc[i][j] = (f32x4){0.f, 0.f, 0.f, 0.f};
  const int fr = lane & 15, fq = lane >> 4;

  for (int k0 = 0; k0 < Klen; k0 += BK) {
    #pragma unroll
    for (int p = 0; p < PA; p++) {
      int seg = wid * PA + p;
      gload16(A + (long)(tileM + seg * 8 + srow) * lda + k0 + scol, &As[seg * 512]);
    }
    #pragma unroll
    for (int p = 0; p < PW; p++) {
      int seg = wid * PW + p;
      gload16(W + (long)(tileN + seg * 8 + srow) * ldw + k0 + scol, &Ws[seg * 512]);
    }
    __syncthreads();
    #pragma unroll
    for (int kk = 0; kk < BK; kk += 32) {
      s16x8 af[MR], bf[NR];
      #pragma unroll
      for (int i = 0; i < MR; i++)
        af[i] = *(const s16x8*)(&As[(wr * WSM + i * 16 + fr) * BK + kk + fq * 8]);
      #pragma unroll
      for (int j = 0; j < NR; j++)
        bf[j] = *(const s16x8*)(&Ws[(wc * WSN + j * 16 + fr) * BK + kk + fq * 8]);
      #pragma unroll
      for (int i = 0; i < MR; i++)
        #pragma unroll
        for (int j = 0; j < NR; j++)
          acc[i][j] = __builtin_amdgcn_mfma_f32_16x16x32_bf16(af[i], bf[j], acc[i][j], 0, 0, 0);
    }
    __syncthreads();
  }

  if constexpr (EPI == 2) {
    static_assert(WR == 1 && BM == 64, "softmax epilogue needs full-M wave");
    #pragma unroll
    for (int i = 0; i < MR; i++)
      #pragma unroll
      for (int j = 0; j < NR; j++)
        #pragma unroll
        for (int q = 0; q < 4; q++) acc[i][j][q] *= alpha;
    float inv[NR];
    #pragma unroll
    for (int j = 0; j < NR; j++) {
      float mx = -1e30f;
      #pragma unroll
      for (int i = 0; i < MR; i++)
        #pragma unroll
        for (int q = 0; q < 4; q++) mx = fmaxf(mx, acc[i][j][q]);
      mx = fmaxf(mx, __shfl_xor(mx, 16, 64));
      mx = fmaxf(mx, __shfl_xor(mx, 32, 64));
      float sm = 0.f;
      #pragma unroll
      for (int i = 0; i < MR; i++)
        #pragma unroll
        for (int q = 0; q < 4; q++) {
          float e = __expf(acc[i][j][q] - mx);
          acc[i][j][q] = e;
          sm += e;
        }
      sm += __shfl_xor(sm, 16, 64);
      sm += __shfl_xor(sm, 32, 64);
      inv[j] = 1.f / sm;
    }
    float rp[MR][4];
    #pragma unroll
    for (int i = 0; i < MR; i++)
      #pragma unroll
      for (int q = 0; q < 4; q++) rp[i][q] = 0.f;
    unsigned short* Cs = (unsigned short*)C;
    #pragma unroll
    for (int i = 0; i < MR; i++)
      #pragma unroll
      for (int j = 0; j < NR; j++)
        #pragma unroll
        for (int q = 0; q < 4; q++) {
          float a = acc[i][j][q] * inv[j];
          rp[i][q] += a;
          Cs[(long)(i * 16 + fq * 4 + q) * N + tileN + wc * WSN + j * 16 + fr] = f2bf(a);
        }
    #pragma unroll
    for (int off = 1; off <= 8; off <<= 1)
      #pragma unroll
      for (int i = 0; i < MR; i++)
        #pragma unroll
        for (int q = 0; q < 4; q++) rp[i][q] += __shfl_xor(rp[i][q], off, 64);
    if (fr == 0) {
      const int rld = gridDim.x * WC;
      #pragma unroll
      for (int i = 0; i < MR; i++)
        #pragma unroll
        for (int q = 0; q < 4; q++)
          rs_part[((long)zb * 64 + i * 16 + fq * 4 + q) * rld + blockIdx.x * WC + wc] = rp[i][q];
    }
    return;
  }

  #pragma unroll
  for (int i = 0; i < MR; i++) {
    const int mbase = tileM + wr * WSM + i * 16 + fq * 4;
    #pragma unroll
    for (int j = 0; j < NR; j++) {
      const int n = tileN + wc * WSN + j * 16 + fr;
      const float bv = bias ? bias[n] : 0.f;
      #pragma unroll
      for (int q = 0; q < 4; q++) {
        float v = acc[i][j][q] * alpha + bv;
        if constexpr (sizeof(CT) == 2)
          C[(long)(mbase + q) * N + coff + n] = f2bf(v);
        else
          C[(long)(mbase + q) * N + coff + n] = v;
      }
    }
  }
}

// ---- reduce 8 bf16 K-splits; in-block rowsum of rs_part (256 partials) -> rowinv; scale; bf16 ----
__global__ __launch_bounds__(256) void upd_reduce_k(const unsigned short* __restrict__ part,
                                                    const float* __restrict__ rs_part,
                                                    unsigned short* __restrict__ out) {
  const int row = blockIdx.x;  // b*64 + k
  const int tid = threadIdx.x;
  float s = rs_part[(long)row * 256 + tid];
  #pragma unroll
  for (int off = 32; off; off >>= 1) s += __shfl_xor(s, off, 64);
  __shared__ float sb[4];
  if ((tid & 63) == 0) sb[tid >> 6] = s;
  __syncthreads();
  const float inv = 1.f / (sb[0] + sb[1] + sb[2] + sb[3] + 1e-6f);
  const unsigned short* base =
      part + (long)(row >> 6) * 8 * 65536 + (long)(row & 63) * 1024 + tid * 4;
  float ax = 0.f, ay = 0.f, az = 0.f, aw = 0.f;
  #pragma unroll
  for (int sp = 0; sp < 8; sp++) {
    ushort4 v = *(const ushort4*)(base + (long)sp * 65536);
    ax += bf2f(v.x); ay += bf2f(v.y); az += bf2f(v.z); aw += bf2f(v.w);
  }
  ushort4 o;
  o.x = f2bf(ax * inv); o.y = f2bf(ay * inv);
  o.z = f2bf(az * inv); o.w = f2bf(aw * inv);
  ((ushort4*)out)[(long)row * 256 + tid] = o;
}

// ---- GRU combine (bf16 gi / gh-in-qgh) + fused rmsnorm of the new slots ----
__global__ __launch_bounds__(256) void gru_k(const unsigned short* __restrict__ gi,
                                             const unsigned short* __restrict__ qgh,
                                             const float* __restrict__ h,
                                             const float* __restrict__ snw,
                                             float* __restrict__ out,
                                             unsigned short* __restrict__ out_bf,
                                             unsigned short* __restrict__ sn_out) {
  const int r = blockIdx.x;
  const int tid = threadIdx.x;
  const int c = tid * 4;
  const unsigned short* gip = gi + (long)r * 3072;
  const unsigned short* ghp = qgh + (long)r * 4096 + 1024;
  ushort4 iru = *(const ushort4*)(gip + c);
  ushort4 izu = *(const ushort4*)(gip + 1024 + c);
  ushort4 inu = *(const ushort4*)(gip + 2048 + c);
  ushort4 hru = *(const ushort4*)(ghp + c);
  ushort4 hzu = *(const ushort4*)(ghp + 1024 + c);
  ushort4 hnu = *(const ushort4*)(ghp + 2048 + c);
  float4 hv = *(const float4*)(h + (long)r * 1024 + c);
  float4 o;
  { float rr = sigm(bf2f(iru.x) + bf2f(hru.x)), zz = sigm(bf2f(izu.x) + bf2f(hzu.x));
    float nn = tanhf(bf2f(inu.x) + rr * bf2f(hnu.x)); o.x = (1.f - zz) * nn + zz * hv.x; }
  { float rr = sigm(bf2f(iru.y) + bf2f(hru.y)), zz = sigm(bf2f(izu.y) + bf2f(hzu.y));
    float nn = tanhf(bf2f(inu.y) + rr * bf2f(hnu.y)); o.y = (1.f - zz) * nn + zz * hv.y; }
  { float rr = sigm(bf2f(iru.z) + bf2f(hru.z)), zz = sigm(bf2f(izu.z) + bf2f(hzu.z));
    float nn = tanhf(bf2f(inu.z) + rr * bf2f(hnu.z)); o.z = (1.f - zz) * nn + zz * hv.z; }
  { float rr = sigm(bf2f(iru.w) + bf2f(hru.w)), zz = sigm(bf2f(izu.w) + bf2f(hzu.w));
    float nn = tanhf(bf2f(inu.w) + rr * bf2f(hnu.w)); o.w = (1.f - zz) * nn + zz * hv.w; }
  *(float4*)(out + (long)r * 1024 + c) = o;
  ushort4 ob;
  ob.x = f2bf(o.x); ob.y = f2bf(o.y); ob.z = f2bf(o.z); ob.w = f2bf(o.w);
  *(ushort4*)(out_bf + (long)r * 1024 + c) = ob;
  float ss = o.x * o.x + o.y * o.y + o.z * o.z + o.w * o.w;
  #pragma unroll
  for (int off = 32; off; off >>= 1) ss += __shfl_xor(ss, off, 64);
  __shared__ float sb[4];
  if ((tid & 63) == 0) sb[tid >> 6] = ss;
  __syncthreads();
  const float tot = sb[0] + sb[1] + sb[2] + sb[3];
  const float rs = rsqrtf(tot * (1.0f / 1024.0f) + 1e-6f);
  float4 wv = *(const float4*)(snw + c);
  ushort4 so;
  so.x = f2bf(o.x * rs * wv.x); so.y = f2bf(o.y * rs * wv.y);
  so.z = f2bf(o.z * rs * wv.z); so.w = f2bf(o.w * rs * wv.w);
  *(ushort4*)(sn_out + (long)r * 1024 + c) = so;
}

extern "C" void kernel_launch(void* const* d_in, const int* in_sizes, int n_in,
                              void* d_out, int out_size, void* d_ws, size_t ws_size,
                              hipStream_t stream) {
  const float* slots_in = (const float*)d_in[0];
  const float* P        = (const float*)d_in[1];
  const float* Wq       = (const float*)d_in[2];
  const float* Wk       = (const float*)d_in[3];
  const float* Wv       = (const float*)d_in[4];
  const float* wi       = (const float*)d_in[5];
  const float* wh       = (const float*)d_in[6];
  const float* bi       = (const float*)d_in[7];
  const float* bh       = (const float*)d_in[8];
  const float* snw      = (const float*)d_in[9];
  const float* inw      = (const float*)d_in[10];

  const size_t MB = 1024ull * 1024ull;
  char* ws = (char*)d_ws;
  unsigned short* Pn    = (unsigned short*)(ws + 0);        // 64MB [b][m][d] bf16 (persists)
  unsigned short* Pnt   = (unsigned short*)(ws + 64 * MB);  // 64MB [b][d][m] bf16 (persists)
  char* S               = ws + 128 * MB;                    // iteration region
  unsigned short* sn    = (unsigned short*)(S);             // 1MB
  unsigned short* qgh   = (unsigned short*)(S + 1 * MB);    // 4MB [512][4096]: qm | gh
  unsigned short* attnb = (unsigned short*)(S + 5 * MB);    // 4MB
  unsigned short* updb  = (unsigned short*)(S + 9 * MB);    // 1MB (t * rowinv, bf16)
  unsigned short* slotsb= (unsigned short*)(S + 10 * MB);   // 1MB
  unsigned short* gi_b  = (unsigned short*)(S + 11 * MB);   // 3MB [512][3072]
  unsigned short* Cpart = (unsigned short*)(S + 14 * MB);   // 8MB bf16 [64][64][1024]
  float* rs_part        = (float*)(S + 22 * MB);            // 512KB [512][256]
  unsigned short* wqt   = (unsigned short*)(S + 23 * MB);   // 2MB (Wq^T bf16)
  unsigned short* wvt   = (unsigned short*)(S + 25 * MB);   // 2MB (Wv^T bf16)
  unsigned short* wh_b  = (unsigned short*)(S + 27 * MB);   // 6MB
  unsigned short* wkt   = (unsigned short*)(S + 33 * MB);   // 2MB } combined A4 [4096][1024]
  unsigned short* wi_b  = (unsigned short*)(S + 35 * MB);   // 6MB }
  unsigned short* m1_b  = (unsigned short*)(S + 41 * MB);   // 2MB } combined C4 [4096][1024]
  unsigned short* m2_b  = (unsigned short*)(S + 43 * MB);   // 6MB }
  float* slots          = (float*)(ws + 196 * MB);          // 2MB

  // ---- prologue (3 dispatches) ----
  prep_k<<<4352, 256, 0, stream>>>(Wq, Wk, Wv, wi, wh, slots_in, snw,
                                   wqt, wkt, wvt, wi_b, wh_b, sn, slotsb);
  rmstp_k<<<512, 256, 0, stream>>>(P, inw, Pn, Pnt);
  // merged M1 = Wk^T @ Wq (y<16) and M2 = wi @ Wv (y>=16); combined A/C buffers
  gemm_bt<64, 64, 2, 2, unsigned short, 0, 1, 0, 1>
      <<<dim3(16, 64, 1), 256, 0, stream>>>(wkt, wqt, m1_b, 1024, 1024, 1024, 1024,
                                            0, 0, 0, nullptr, nullptr, 1.f, nullptr,
                                            nullptr, wvt);

  // ---- 3 iterations (6 dispatches each) ----
  for (int it = 0; it < 3; ++it) {
    // merged qm+gh: z=0 -> qm = sn@M1^T; z=1..3 -> gh slab = slotsb@wh^T+bh
    gemm_bt<64, 64, 2, 2, unsigned short, 0, 1, 1, 0>
        <<<dim3(16, 8, 4), 256, 0, stream>>>(sn, m1_b, qgh, 4096, 1024, 1024, 1024,
                                             0, 0, 0, nullptr, bh, 1.f, nullptr,
                                             slotsb, wh_b);
    // attn[b][k][m] = softmax_k((qm_b @ Pn_b^T)/32) + row partials (BN=64, 512 blocks)
    gemm_bt<64, 64, 1, 4, unsigned short, 2, 1, 0, 0>
        <<<dim3(64, 1, 8), 256, 0, stream>>>(qgh, Pn, attnb, 4096, 1024, 4096, 1024,
                                             64L * 4096, 4096L * 1024, 64L * 4096,
                                             nullptr, nullptr, 0.03125f, rs_part,
                                             nullptr, nullptr);
    // t partials (bf16): attn_b @ Pnt_b^T, K=4096 split 8x512 (1024 blocks)
    gemm_bt<64, 64, 2, 2, unsigned short, 0, 8, 0, 0>
        <<<dim3(16, 1, 64), 256, 0, stream>>>(attnb, Pnt, Cpart, 1024, 512, 4096, 4096,
                                              64L * 4096, 1024L * 4096, 64L * 1024,
                                              nullptr, nullptr, 1.f, nullptr,
                                              nullptr, nullptr);
    upd_reduce_k<<<512, 256, 0, stream>>>(Cpart, rs_part, updb);
    // gi = (t*rowinv) @ M2^T + bi -> bf16 [512][3072]
    gemm_bt<64, 64, 2, 2, unsigned short, 0, 1, 0, 0>
        <<<dim3(48, 8, 1), 256, 0, stream>>>(updb, m2_b, gi_b, 3072, 1024, 1024, 1024,
                                             0, 0, 0, bi, nullptr, 1.f, nullptr,
                                             nullptr, nullptr);
    const float* hsrc = (it == 0) ? slots_in : slots;
    float* dst = (it == 2) ? (float*)d_out : slots;
    gru_k<<<512, 256, 0, stream>>>(gi_b, qgh, hsrc, snw, dst, slotsb, sn);
  }
}

// Round 16
// 331.127 us; speedup vs baseline: 1.1225x; 1.1225x over previous
//
#include <hip/hip_runtime.h>

typedef __attribute__((ext_vector_type(4))) float f32x4;
typedef __attribute__((ext_vector_type(8))) short s16x8;

static __device__ __forceinline__ unsigned short f2bf(float f) {
  unsigned int u = __builtin_bit_cast(unsigned int, f);
  u += 0x7fffu + ((u >> 16) & 1u);
  return (unsigned short)(u >> 16);
}
static __device__ __forceinline__ float bf2f(unsigned short u) {
  return __builtin_bit_cast(float, (unsigned int)u << 16);
}
static __device__ __forceinline__ float sigm(float x) { return 1.0f / (1.0f + __expf(-x)); }

// async global->LDS, 16B per lane. LDS dest = wave-uniform base + lane*16.
static __device__ __forceinline__ void gload16(const unsigned short* g, unsigned short* l) {
  __builtin_amdgcn_global_load_lds(
      (const __attribute__((address_space(1))) void*)g,
      (__attribute__((address_space(3))) void*)l, 16, 0, 0);
}

// ---------------- rmsnorm rows of length 1024: fp32 -> bf16 ----------------
__global__ __launch_bounds__(256) void rmsnorm_k(const float* __restrict__ x,
                                                 const float* __restrict__ w,
                                                 unsigned short* __restrict__ y) {
  const int row = blockIdx.x;
  const int tid = threadIdx.x;
  const float4* xp = (const float4*)(x + (long)row * 1024);
  float4 v = xp[tid];
  float ss = v.x * v.x + v.y * v.y + v.z * v.z + v.w * v.w;
  #pragma unroll
  for (int off = 32; off; off >>= 1) ss += __shfl_xor(ss, off, 64);
  __shared__ float sb[4];
  if ((tid & 63) == 0) sb[tid >> 6] = ss;
  __syncthreads();
  float tot = sb[0] + sb[1] + sb[2] + sb[3];
  float rs = rsqrtf(tot * (1.0f / 1024.0f) + 1e-6f);
  const float4* wp = (const float4*)w;
  float4 wv = wp[tid];
  ushort4 o;
  o.x = f2bf(v.x * rs * wv.x);
  o.y = f2bf(v.y * rs * wv.y);
  o.z = f2bf(v.z * rs * wv.z);
  o.w = f2bf(v.w * rs * wv.w);
  ((ushort4*)y)[(long)row * 256 + tid] = o;
}

// ---------------- bf16 transpose: Pn[b][4096 m][1024 d] -> Pnt[b][1024 d][4096 m] ----------------
__global__ __launch_bounds__(256) void tp_k(const unsigned short* __restrict__ in,
                                            unsigned short* __restrict__ out) {
  __shared__ unsigned short t[64][65];
  const int x = blockIdx.x;
  const int b = x >> 10;
  const int mt = (x & 1023) >> 4;
  const int dt = x & 15;
  const int tid = threadIdx.x;
  const long ibase = (long)b * 4096 * 1024 + (long)mt * 64 * 1024 + dt * 64;
  #pragma unroll
  for (int i = 0; i < 4; i++) {
    int idx = tid + i * 256;
    int r = idx >> 4, c4 = (idx & 15) * 4;
    ushort4 v = *(const ushort4*)(in + ibase + (long)r * 1024 + c4);
    t[r][c4] = v.x; t[r][c4 + 1] = v.y; t[r][c4 + 2] = v.z; t[r][c4 + 3] = v.w;
  }
  __syncthreads();
  const long obase = (long)b * 1024 * 4096 + (long)dt * 64 * 4096 + mt * 64;
  #pragma unroll
  for (int i = 0; i < 4; i++) {
    int idx = tid + i * 256;
    int r = idx >> 4, c4 = (idx & 15) * 4;
    ushort4 o;
    o.x = t[c4][r]; o.y = t[c4 + 1][r]; o.z = t[c4 + 2][r]; o.w = t[c4 + 3][r];
    *(ushort4*)(out + obase + (long)r * 4096 + c4) = o;
  }
}

// ---------------- fp32->bf16 convert chunk ----------------
static __device__ __forceinline__ void cvt_chunk(const float* __restrict__ in,
                                                 unsigned short* __restrict__ out, long i) {
  const float4* p = (const float4*)in;
  float4 a = p[i * 2], b = p[i * 2 + 1];
  ushort4 lo, hi;
  lo.x = f2bf(a.x); lo.y = f2bf(a.y); lo.z = f2bf(a.z); lo.w = f2bf(a.w);
  hi.x = f2bf(b.x); hi.y = f2bf(b.y); hi.z = f2bf(b.z); hi.w = f2bf(b.w);
  ushort4* o = (ushort4*)out;
  o[i * 2] = lo;
  o[i * 2 + 1] = hi;
}

// ---------------- combined prologue prep ----------------
// grid 4352: [0,768)    transpose-cvt Wq/Wk/Wv -> wqt/wkt/wvt (64x64 tiles)
//            [768,3840) cvt wi (1536 blocks) then wh (1536 blocks)
//            [3840,4352) rmsnorm(slots_in) -> sn + raw bf16 -> slotsb
__global__ __launch_bounds__(256) void prep_k(
    const float* __restrict__ Wq, const float* __restrict__ Wk, const float* __restrict__ Wv,
    const float* __restrict__ wi, const float* __restrict__ wh,
    const float* __restrict__ slots_in, const float* __restrict__ snw,
    unsigned short* __restrict__ wqt, unsigned short* __restrict__ wkt,
    unsigned short* __restrict__ wvt, unsigned short* __restrict__ wi_b,
    unsigned short* __restrict__ wh_b, unsigned short* __restrict__ sn,
    unsigned short* __restrict__ slotsb) {
  __shared__ float tile[64][65];
  const int x = blockIdx.x;
  const int tid = threadIdx.x;
  if (x < 768) {
    const int z = x >> 8, t = x & 255;
    const float* in = (z == 0) ? Wq : (z == 1) ? Wk : Wv;
    unsigned short* out = (z == 0) ? wqt : (z == 1) ? wkt : wvt;
    const int r0 = (t >> 4) * 64, c0 = (t & 15) * 64;
    #pragma unroll
    for (int i = 0; i < 4; i++) {
      int idx = tid + i * 256;
      int r = idx >> 4, c4 = (idx & 15) * 4;
      float4 v = *(const float4*)(in + (long)(r0 + r) * 1024 + c0 + c4);
      tile[r][c4] = v.x; tile[r][c4 + 1] = v.y; tile[r][c4 + 2] = v.z; tile[r][c4 + 3] = v.w;
    }
    __syncthreads();
    #pragma unroll
    for (int i = 0; i < 4; i++) {
      int idx = tid + i * 256;
      int c = idx >> 4, r4 = (idx & 15) * 4;
      ushort4 o;
      o.x = f2bf(tile[r4][c]);     o.y = f2bf(tile[r4 + 1][c]);
      o.z = f2bf(tile[r4 + 2][c]); o.w = f2bf(tile[r4 + 3][c]);
      *(ushort4*)(out + (long)(c0 + c) * 1024 + r0 + r4) = o;
    }
  } else if (x < 3840) {
    const int y = x - 768;
    if (y < 1536) cvt_chunk(wi, wi_b, (long)y * 256 + tid);
    else          cvt_chunk(wh, wh_b, (long)(y - 1536) * 256 + tid);
  } else {
    const int row = x - 3840;
    const float4* xp = (const float4*)(slots_in + (long)row * 1024);
    float4 v = xp[tid];
    float ss = v.x * v.x + v.y * v.y + v.z * v.z + v.w * v.w;
    #pragma unroll
    for (int off = 32; off; off >>= 1) ss += __shfl_xor(ss, off, 64);
    float* sb = &tile[0][0];
    if ((tid & 63) == 0) sb[tid >> 6] = ss;
    __syncthreads();
    float tot = sb[0] + sb[1] + sb[2] + sb[3];
    float rs = rsqrtf(tot * (1.0f / 1024.0f) + 1e-6f);
    float4 wv = ((const float4*)snw)[tid];
    ushort4 o;
    o.x = f2bf(v.x * rs * wv.x); o.y = f2bf(v.y * rs * wv.y);
    o.z = f2bf(v.z * rs * wv.z); o.w = f2bf(v.w * rs * wv.w);
    ((ushort4*)sn)[(long)row * 256 + tid] = o;
    ushort4 r;
    r.x = f2bf(v.x); r.y = f2bf(v.y); r.z = f2bf(v.z); r.w = f2bf(v.w);
    ((ushort4*)slotsb)[(long)row * 256 + tid] = r;
  }
}

// ---------------- GEMM: C = alpha * A[M][K] @ W[N][K]^T (+bias) ----------------
// EPI: 0 = plain store; 2 = softmax over M(=64) -> bf16 attn + row partials.
// SPLIT: K-split batching. QGH: z=0 -> A/W cols[0,1024); z>0 -> A2/W2 slab.
// M12: blockIdx.y >= 16 switches W to W2 (combined A/C buffers).
template <int BM, int BN, int WR, int WC, typename CT, int EPI, int SPLIT, int QGH, int M12>
__global__ __launch_bounds__(WR * WC * 64) void gemm_bt(
    const unsigned short* __restrict__ A, const unsigned short* __restrict__ W,
    CT* __restrict__ C, int N, int Klen, int lda, int ldw,
    long sA, long sW, long sC, const float* __restrict__ bias,
    const float* __restrict__ bias2, float alpha, float* __restrict__ rs_part,
    const unsigned short* __restrict__ A2, const unsigned short* __restrict__ W2) {
  constexpr int BK = 64;
  constexpr int NT = WR * WC * 64;
  static_assert(NT == 256, "256 threads");
  constexpr int WSM = BM / WR, WSN = BN / WC;
  constexpr int MR = WSM / 16, NR = WSN / 16;
  constexpr int SEG_A = BM / 8, SEG_W = BN / 8;
  constexpr int PA = SEG_A / 4, PW = SEG_W / 4;
  static_assert(SEG_A % 4 == 0 && SEG_W % 4 == 0, "seg divisibility");
  __shared__ unsigned short As[BM * BK];
  __shared__ unsigned short Ws[BN * BK];
  const int tid = threadIdx.x, lane = tid & 63, wid = tid >> 6;
  const int wr = wid / WC, wc = wid % WC;
  const int tileN = blockIdx.x * BN, tileM = blockIdx.y * BM;
  int coff = 0;
  int zb = 0;
  if constexpr (QGH) {
    const int zz = blockIdx.z;
    if (zz > 0) {
      A = A2;
      W = W2 + (long)(zz - 1) * 1024 * ldw;
      bias = bias2 + (zz - 1) * 1024;
      coff = zz * 1024;
    }
  } else if constexpr (M12) {
    if (blockIdx.y >= 16) W = W2;
  } else {
    zb = blockIdx.z / SPLIT;
    const int zs = blockIdx.z % SPLIT;
    A += (long)zb * sA + (long)zs * Klen;
    W += (long)zb * sW + (long)zs * Klen;
    C += (long)blockIdx.z * sC;
  }
  const int srow = lane >> 3;
  const int scol = (lane & 7) * 8;
  f32x4 acc[MR][NR];
  #pragma unroll
  for (int i = 0; i < MR; i++)
    #pragma unroll
    for (int j = 0; j < NR; j++) acc[i][j] = (f32x4){0.f, 0.f, 0.f, 0.f};
  const int fr = lane & 15, fq = lane >> 4;

  for (int k0 = 0; k0 < Klen; k0 += BK) {
    #pragma unroll
    for (int p = 0; p < PA; p++) {
      int seg = wid * PA + p;
      gload16(A + (long)(tileM + seg * 8 + srow) * lda + k0 + scol, &As[seg * 512]);
    }
    #pragma unroll
    for (int p = 0; p < PW; p++) {
      int seg = wid * PW + p;
      gload16(W + (long)(tileN + seg * 8 + srow) * ldw + k0 + scol, &Ws[seg * 512]);
    }
    __syncthreads();
    #pragma unroll
    for (int kk = 0; kk < BK; kk += 32) {
      s16x8 af[MR], bf[NR];
      #pragma unroll
      for (int i = 0; i < MR; i++)
        af[i] = *(const s16x8*)(&As[(wr * WSM + i * 16 + fr) * BK + kk + fq * 8]);
      #pragma unroll
      for (int j = 0; j < NR; j++)
        bf[j] = *(const s16x8*)(&Ws[(wc * WSN + j * 16 + fr) * BK + kk + fq * 8]);
      #pragma unroll
      for (int i = 0; i < MR; i++)
        #pragma unroll
        for (int j = 0; j < NR; j++)
          acc[i][j] = __builtin_amdgcn_mfma_f32_16x16x32_bf16(af[i], bf[j], acc[i][j], 0, 0, 0);
    }
    __syncthreads();
  }

  if constexpr (EPI == 2) {
    static_assert(WR == 1 && BM == 64, "softmax epilogue needs full-M wave");
    #pragma unroll
    for (int i = 0; i < MR; i++)
      #pragma unroll
      for (int j = 0; j < NR; j++)
        #pragma unroll
        for (int q = 0; q < 4; q++) acc[i][j][q] *= alpha;
    float inv[NR];
    #pragma unroll
    for (int j = 0; j < NR; j++) {
      float mx = -1e30f;
      #pragma unroll
      for (int i = 0; i < MR; i++)
        #pragma unroll
        for (int q = 0; q < 4; q++) mx = fmaxf(mx, acc[i][j][q]);
      mx = fmaxf(mx, __shfl_xor(mx, 16, 64));
      mx = fmaxf(mx, __shfl_xor(mx, 32, 64));
      float sm = 0.f;
      #pragma unroll
      for (int i = 0; i < MR; i++)
        #pragma unroll
        for (int q = 0; q < 4; q++) {
          float e = __expf(acc[i][j][q] - mx);
          acc[i][j][q] = e;
          sm += e;
        }
      sm += __shfl_xor(sm, 16, 64);
      sm += __shfl_xor(sm, 32, 64);
      inv[j] = 1.f / sm;
    }
    float rp[MR][4];
    #pragma unroll
    for (int i = 0; i < MR; i++)
      #pragma unroll
      for (int q = 0; q < 4; q++) rp[i][q] = 0.f;
    unsigned short* Cs = (unsigned short*)C;
    #pragma unroll
    for (int i = 0; i < MR; i++)
      #pragma unroll
      for (int j = 0; j < NR; j++)
        #pragma unroll
        for (int q = 0; q < 4; q++) {
          float a = acc[i][j][q] * inv[j];
          rp[i][q] += a;
          Cs[(long)(i * 16 + fq * 4 + q) * N + tileN + wc * WSN + j * 16 + fr] = f2bf(a);
        }
    #pragma unroll
    for (int off = 1; off <= 8; off <<= 1)
      #pragma unroll
      for (int i = 0; i < MR; i++)
        #pragma unroll
        for (int q = 0; q < 4; q++) rp[i][q] += __shfl_xor(rp[i][q], off, 64);
    if (fr == 0) {
      const int rld = gridDim.x * WC;
      #pragma unroll
      for (int i = 0; i < MR; i++)
        #pragma unroll
        for (int q = 0; q < 4; q++)
          rs_part[((long)zb * 64 + i * 16 + fq * 4 + q) * rld + blockIdx.x * WC + wc] = rp[i][q];
    }
    return;
  }

  #pragma unroll
  for (int i = 0; i < MR; i++) {
    const int mbase = tileM + wr * WSM + i * 16 + fq * 4;
    #pragma unroll
    for (int j = 0; j < NR; j++) {
      const int n = tileN + wc * WSN + j * 16 + fr;
      const float bv = bias ? bias[n] : 0.f;
      #pragma unroll
      for (int q = 0; q < 4; q++) {
        float v = acc[i][j][q] * alpha + bv;
        if constexpr (sizeof(CT) == 2)
          C[(long)(mbase + q) * N + coff + n] = f2bf(v);
        else
          C[(long)(mbase + q) * N + coff + n] = v;
      }
    }
  }
}

// ---- reduce 8 bf16 K-splits; in-block rowsum of rs_part (256 partials) -> rowinv; scale; bf16 ----
__global__ __launch_bounds__(256) void upd_reduce_k(const unsigned short* __restrict__ part,
                                                    const float* __restrict__ rs_part,
                                                    unsigned short* __restrict__ out) {
  const int row = blockIdx.x;  // b*64 + k
  const int tid = threadIdx.x;
  float s = rs_part[(long)row * 256 + tid];
  #pragma unroll
  for (int off = 32; off; off >>= 1) s += __shfl_xor(s, off, 64);
  __shared__ float sb[4];
  if ((tid & 63) == 0) sb[tid >> 6] = s;
  __syncthreads();
  const float inv = 1.f / (sb[0] + sb[1] + sb[2] + sb[3] + 1e-6f);
  const unsigned short* base =
      part + (long)(row >> 6) * 8 * 65536 + (long)(row & 63) * 1024 + tid * 4;
  float ax = 0.f, ay = 0.f, az = 0.f, aw = 0.f;
  #pragma unroll
  for (int sp = 0; sp < 8; sp++) {
    ushort4 v = *(const ushort4*)(base + (long)sp * 65536);
    ax += bf2f(v.x); ay += bf2f(v.y); az += bf2f(v.z); aw += bf2f(v.w);
  }
  ushort4 o;
  o.x = f2bf(ax * inv); o.y = f2bf(ay * inv);
  o.z = f2bf(az * inv); o.w = f2bf(aw * inv);
  ((ushort4*)out)[(long)row * 256 + tid] = o;
}

// ---- GRU combine (bf16 gi / gh-in-qgh) + fused rmsnorm of the new slots ----
__global__ __launch_bounds__(256) void gru_k(const unsigned short* __restrict__ gi,
                                             const unsigned short* __restrict__ qgh,
                                             const float* __restrict__ h,
                                             const float* __restrict__ snw,
                                             float* __restrict__ out,
                                             unsigned short* __restrict__ out_bf,
                                             unsigned short* __restrict__ sn_out) {
  const int r = blockIdx.x;
  const int tid = threadIdx.x;
  const int c = tid * 4;
  const unsigned short* gip = gi + (long)r * 3072;
  const unsigned short* ghp = qgh + (long)r * 4096 + 1024;
  ushort4 iru = *(const ushort4*)(gip + c);
  ushort4 izu = *(const ushort4*)(gip + 1024 + c);
  ushort4 inu = *(const ushort4*)(gip + 2048 + c);
  ushort4 hru = *(const ushort4*)(ghp + c);
  ushort4 hzu = *(const ushort4*)(ghp + 1024 + c);
  ushort4 hnu = *(const ushort4*)(ghp + 2048 + c);
  float4 hv = *(const float4*)(h + (long)r * 1024 + c);
  float4 o;
  { float rr = sigm(bf2f(iru.x) + bf2f(hru.x)), zz = sigm(bf2f(izu.x) + bf2f(hzu.x));
    float nn = tanhf(bf2f(inu.x) + rr * bf2f(hnu.x)); o.x = (1.f - zz) * nn + zz * hv.x; }
  { float rr = sigm(bf2f(iru.y) + bf2f(hru.y)), zz = sigm(bf2f(izu.y) + bf2f(hzu.y));
    float nn = tanhf(bf2f(inu.y) + rr * bf2f(hnu.y)); o.y = (1.f - zz) * nn + zz * hv.y; }
  { float rr = sigm(bf2f(iru.z) + bf2f(hru.z)), zz = sigm(bf2f(izu.z) + bf2f(hzu.z));
    float nn = tanhf(bf2f(inu.z) + rr * bf2f(hnu.z)); o.z = (1.f - zz) * nn + zz * hv.z; }
  { float rr = sigm(bf2f(iru.w) + bf2f(hru.w)), zz = sigm(bf2f(izu.w) + bf2f(hzu.w));
    float nn = tanhf(bf2f(inu.w) + rr * bf2f(hnu.w)); o.w = (1.f - zz) * nn + zz * hv.w; }
  *(float4*)(out + (long)r * 1024 + c) = o;
  ushort4 ob;
  ob.x = f2bf(o.x); ob.y = f2bf(o.y); ob.z = f2bf(o.z); ob.w = f2bf(o.w);
  *(ushort4*)(out_bf + (long)r * 1024 + c) = ob;
  float ss = o.x * o.x + o.y * o.y + o.z * o.z + o.w * o.w;
  #pragma unroll
  for (int off = 32; off; off >>= 1) ss += __shfl_xor(ss, off, 64);
  __shared__ float sb[4];
  if ((tid & 63) == 0) sb[tid >> 6] = ss;
  __syncthreads();
  const float tot = sb[0] + sb[1] + sb[2] + sb[3];
  const float rs = rsqrtf(tot * (1.0f / 1024.0f) + 1e-6f);
  float4 wv = *(const float4*)(snw + c);
  ushort4 so;
  so.x = f2bf(o.x * rs * wv.x); so.y = f2bf(o.y * rs * wv.y);
  so.z = f2bf(o.z * rs * wv.z); so.w = f2bf(o.w * rs * wv.w);
  *(ushort4*)(sn_out + (long)r * 1024 + c) = so;
}

extern "C" void kernel_launch(void* const* d_in, const int* in_sizes, int n_in,
                              void* d_out, int out_size, void* d_ws, size_t ws_size,
                              hipStream_t stream) {
  const float* slots_in = (const float*)d_in[0];
  const float* P        = (const float*)d_in[1];
  const float* Wq       = (const float*)d_in[2];
  const float* Wk       = (const float*)d_in[3];
  const float* Wv       = (const float*)d_in[4];
  const float* wi       = (const float*)d_in[5];
  const float* wh       = (const float*)d_in[6];
  const float* bi       = (const float*)d_in[7];
  const float* bh       = (const float*)d_in[8];
  const float* snw      = (const float*)d_in[9];
  const float* inw      = (const float*)d_in[10];

  const size_t MB = 1024ull * 1024ull;
  char* ws = (char*)d_ws;
  unsigned short* Pn    = (unsigned short*)(ws + 0);        // 64MB [b][m][d] bf16 (persists)
  unsigned short* Pnt   = (unsigned short*)(ws + 64 * MB);  // 64MB [b][d][m] bf16 (persists)
  char* S               = ws + 128 * MB;                    // iteration region
  unsigned short* sn    = (unsigned short*)(S);             // 1MB
  unsigned short* qgh   = (unsigned short*)(S + 1 * MB);    // 4MB [512][4096]: qm | gh
  unsigned short* attnb = (unsigned short*)(S + 5 * MB);    // 4MB
  unsigned short* updb  = (unsigned short*)(S + 9 * MB);    // 1MB (t * rowinv, bf16)
  unsigned short* slotsb= (unsigned short*)(S + 10 * MB);   // 1MB
  unsigned short* gi_b  = (unsigned short*)(S + 11 * MB);   // 3MB [512][3072]
  unsigned short* Cpart = (unsigned short*)(S + 14 * MB);   // 8MB bf16 [64][64][1024]
  float* rs_part        = (float*)(S + 22 * MB);            // 512KB [512][256]
  unsigned short* wqt   = (unsigned short*)(S + 23 * MB);   // 2MB (Wq^T bf16)
  unsigned short* wvt   = (unsigned short*)(S + 25 * MB);   // 2MB (Wv^T bf16)
  unsigned short* wh_b  = (unsigned short*)(S + 27 * MB);   // 6MB
  unsigned short* wkt   = (unsigned short*)(S + 33 * MB);   // 2MB } combined A4 [4096][1024]
  unsigned short* wi_b  = (unsigned short*)(S + 35 * MB);   // 6MB }
  unsigned short* m1_b  = (unsigned short*)(S + 41 * MB);   // 2MB } combined C4 [4096][1024]
  unsigned short* m2_b  = (unsigned short*)(S + 43 * MB);   // 6MB }
  float* slots          = (float*)(ws + 196 * MB);          // 2MB

  // ---- prologue (4 dispatches) ----
  prep_k<<<4352, 256, 0, stream>>>(Wq, Wk, Wv, wi, wh, slots_in, snw,
                                   wqt, wkt, wvt, wi_b, wh_b, sn, slotsb);
  rmsnorm_k<<<32768, 256, 0, stream>>>(P, inw, Pn);
  tp_k<<<8192, 256, 0, stream>>>(Pn, Pnt);
  // merged M1 = Wk^T @ Wq (y<16) and M2 = wi @ Wv (y>=16); combined A/C buffers
  gemm_bt<64, 64, 2, 2, unsigned short, 0, 1, 0, 1>
      <<<dim3(16, 64, 1), 256, 0, stream>>>(wkt, wqt, m1_b, 1024, 1024, 1024, 1024,
                                            0, 0, 0, nullptr, nullptr, 1.f, nullptr,
                                            nullptr, wvt);

  // ---- 3 iterations (6 dispatches each) ----
  for (int it = 0; it < 3; ++it) {
    // merged qm+gh: z=0 -> qm = sn@M1^T; z=1..3 -> gh slab = slotsb@wh^T+bh
    gemm_bt<64, 64, 2, 2, unsigned short, 0, 1, 1, 0>
        <<<dim3(16, 8, 4), 256, 0, stream>>>(sn, m1_b, qgh, 4096, 1024, 1024, 1024,
                                             0, 0, 0, nullptr, bh, 1.f, nullptr,
                                             slotsb, wh_b);
    // attn[b][k][m] = softmax_k((qm_b @ Pn_b^T)/32) + row partials (BN=64, 512 blocks)
    gemm_bt<64, 64, 1, 4, unsigned short, 2, 1, 0, 0>
        <<<dim3(64, 1, 8), 256, 0, stream>>>(qgh, Pn, attnb, 4096, 1024, 4096, 1024,
                                             64L * 4096, 4096L * 1024, 64L * 4096,
                                             nullptr, nullptr, 0.03125f, rs_part,
                                             nullptr, nullptr);
    // t partials (bf16): attn_b @ Pnt_b^T, K=4096 split 8x512 (1024 blocks)
    gemm_bt<64, 64, 2, 2, unsigned short, 0, 8, 0, 0>
        <<<dim3(16, 1, 64), 256, 0, stream>>>(attnb, Pnt, Cpart, 1024, 512, 4096, 4096,
                                              64L * 4096, 1024L * 4096, 64L * 1024,
                                              nullptr, nullptr, 1.f, nullptr,
                                              nullptr, nullptr);
    upd_reduce_k<<<512, 256, 0, stream>>>(Cpart, rs_part, updb);
    // gi = (t*rowinv) @ M2^T + bi -> bf16 [512][3072]
    gemm_bt<64, 64, 2, 2, unsigned short, 0, 1, 0, 0>
        <<<dim3(48, 8, 1), 256, 0, stream>>>(updb, m2_b, gi_b, 3072, 1024, 1024, 1024,
                                             0, 0, 0, bi, nullptr, 1.f, nullptr,
                                             nullptr, nullptr);
    const float* hsrc = (it == 0) ? slots_in : slots;
    float* dst = (it == 2) ? (float*)d_out : slots;
    gru_k<<<512, 256, 0, stream>>>(gi_b, qgh, hsrc, snw, dst, slotsb, sn);
  }
}

// Round 17
// 327.830 us; speedup vs baseline: 1.1338x; 1.0101x over previous
//
#include <hip/hip_runtime.h>

typedef __attribute__((ext_vector_type(4))) float f32x4;
typedef __attribute__((ext_vector_type(8))) short s16x8;

static __device__ __forceinline__ unsigned short f2bf(float f) {
  unsigned int u = __builtin_bit_cast(unsigned int, f);
  u += 0x7fffu + ((u >> 16) & 1u);
  return (unsigned short)(u >> 16);
}
static __device__ __forceinline__ float bf2f(unsigned short u) {
  return __builtin_bit_cast(float, (unsigned int)u << 16);
}
static __device__ __forceinline__ float sigm(float x) { return 1.0f / (1.0f + __expf(-x)); }

// async global->LDS, 16B per lane. LDS dest = wave-uniform base + lane*16.
static __device__ __forceinline__ void gload16(const unsigned short* g, unsigned short* l) {
  __builtin_amdgcn_global_load_lds(
      (const __attribute__((address_space(1))) void*)g,
      (__attribute__((address_space(3))) void*)l, 16, 0, 0);
}

// ---------------- rmsnorm rows of length 1024: fp32 -> bf16 ----------------
__global__ __launch_bounds__(256) void rmsnorm_k(const float* __restrict__ x,
                                                 const float* __restrict__ w,
                                                 unsigned short* __restrict__ y) {
  const int row = blockIdx.x;
  const int tid = threadIdx.x;
  const float4* xp = (const float4*)(x + (long)row * 1024);
  float4 v = xp[tid];
  float ss = v.x * v.x + v.y * v.y + v.z * v.z + v.w * v.w;
  #pragma unroll
  for (int off = 32; off; off >>= 1) ss += __shfl_xor(ss, off, 64);
  __shared__ float sb[4];
  if ((tid & 63) == 0) sb[tid >> 6] = ss;
  __syncthreads();
  float tot = sb[0] + sb[1] + sb[2] + sb[3];
  float rs = rsqrtf(tot * (1.0f / 1024.0f) + 1e-6f);
  const float4* wp = (const float4*)w;
  float4 wv = wp[tid];
  ushort4 o;
  o.x = f2bf(v.x * rs * wv.x);
  o.y = f2bf(v.y * rs * wv.y);
  o.z = f2bf(v.z * rs * wv.z);
  o.w = f2bf(v.w * rs * wv.w);
  ((ushort4*)y)[(long)row * 256 + tid] = o;
}

// ---------------- bf16 transpose: Pn[b][4096 m][1024 d] -> Pnt[b][1024 d][4096 m] ----------------
__global__ __launch_bounds__(256) void tp_k(const unsigned short* __restrict__ in,
                                            unsigned short* __restrict__ out) {
  __shared__ unsigned short t[64][65];
  const int x = blockIdx.x;
  const int b = x >> 10;
  const int mt = (x & 1023) >> 4;
  const int dt = x & 15;
  const int tid = threadIdx.x;
  const long ibase = (long)b * 4096 * 1024 + (long)mt * 64 * 1024 + dt * 64;
  #pragma unroll
  for (int i = 0; i < 4; i++) {
    int idx = tid + i * 256;
    int r = idx >> 4, c4 = (idx & 15) * 4;
    ushort4 v = *(const ushort4*)(in + ibase + (long)r * 1024 + c4);
    t[r][c4] = v.x; t[r][c4 + 1] = v.y; t[r][c4 + 2] = v.z; t[r][c4 + 3] = v.w;
  }
  __syncthreads();
  const long obase = (long)b * 1024 * 4096 + (long)dt * 64 * 4096 + mt * 64;
  #pragma unroll
  for (int i = 0; i < 4; i++) {
    int idx = tid + i * 256;
    int r = idx >> 4, c4 = (idx & 15) * 4;
    ushort4 o;
    o.x = t[c4][r]; o.y = t[c4 + 1][r]; o.z = t[c4 + 2][r]; o.w = t[c4 + 3][r];
    *(ushort4*)(out + obase + (long)r * 4096 + c4) = o;
  }
}

// ---------------- fp32->bf16 convert chunk ----------------
static __device__ __forceinline__ void cvt_chunk(const float* __restrict__ in,
                                                 unsigned short* __restrict__ out, long i) {
  const float4* p = (const float4*)in;
  float4 a = p[i * 2], b = p[i * 2 + 1];
  ushort4 lo, hi;
  lo.x = f2bf(a.x); lo.y = f2bf(a.y); lo.z = f2bf(a.z); lo.w = f2bf(a.w);
  hi.x = f2bf(b.x); hi.y = f2bf(b.y); hi.z = f2bf(b.z); hi.w = f2bf(b.w);
  ushort4* o = (ushort4*)out;
  o[i * 2] = lo;
  o[i * 2 + 1] = hi;
}

// ---------------- combined prologue prep ----------------
// grid 4352: [0,768)    transpose-cvt Wq/Wk/Wv -> wqt/wkt/wvt (64x64 tiles)
//            [768,3840) cvt wi (1536 blocks) then wh (1536 blocks)
//            [3840,4352) rmsnorm(slots_in) -> sn + raw bf16 -> slotsb
__global__ __launch_bounds__(256) void prep_k(
    const float* __restrict__ Wq, const float* __restrict__ Wk, const float* __restrict__ Wv,
    const float* __restrict__ wi, const float* __restrict__ wh,
    const float* __restrict__ slots_in, const float* __restrict__ snw,
    unsigned short* __restrict__ wqt, unsigned short* __restrict__ wkt,
    unsigned short* __restrict__ wvt, unsigned short* __restrict__ wi_b,
    unsigned short* __restrict__ wh_b, unsigned short* __restrict__ sn,
    unsigned short* __restrict__ slotsb) {
  __shared__ float tile[64][65];
  const int x = blockIdx.x;
  const int tid = threadIdx.x;
  if (x < 768) {
    const int z = x >> 8, t = x & 255;
    const float* in = (z == 0) ? Wq : (z == 1) ? Wk : Wv;
    unsigned short* out = (z == 0) ? wqt : (z == 1) ? wkt : wvt;
    const int r0 = (t >> 4) * 64, c0 = (t & 15) * 64;
    #pragma unroll
    for (int i = 0; i < 4; i++) {
      int idx = tid + i * 256;
      int r = idx >> 4, c4 = (idx & 15) * 4;
      float4 v = *(const float4*)(in + (long)(r0 + r) * 1024 + c0 + c4);
      tile[r][c4] = v.x; tile[r][c4 + 1] = v.y; tile[r][c4 + 2] = v.z; tile[r][c4 + 3] = v.w;
    }
    __syncthreads();
    #pragma unroll
    for (int i = 0; i < 4; i++) {
      int idx = tid + i * 256;
      int c = idx >> 4, r4 = (idx & 15) * 4;
      ushort4 o;
      o.x = f2bf(tile[r4][c]);     o.y = f2bf(tile[r4 + 1][c]);
      o.z = f2bf(tile[r4 + 2][c]); o.w = f2bf(tile[r4 + 3][c]);
      *(ushort4*)(out + (long)(c0 + c) * 1024 + r0 + r4) = o;
    }
  } else if (x < 3840) {
    const int y = x - 768;
    if (y < 1536) cvt_chunk(wi, wi_b, (long)y * 256 + tid);
    else          cvt_chunk(wh, wh_b, (long)(y - 1536) * 256 + tid);
  } else {
    const int row = x - 3840;
    const float4* xp = (const float4*)(slots_in + (long)row * 1024);
    float4 v = xp[tid];
    float ss = v.x * v.x + v.y * v.y + v.z * v.z + v.w * v.w;
    #pragma unroll
    for (int off = 32; off; off >>= 1) ss += __shfl_xor(ss, off, 64);
    float* sb = &tile[0][0];
    if ((tid & 63) == 0) sb[tid >> 6] = ss;
    __syncthreads();
    float tot = sb[0] + sb[1] + sb[2] + sb[3];
    float rs = rsqrtf(tot * (1.0f / 1024.0f) + 1e-6f);
    float4 wv = ((const float4*)snw)[tid];
    ushort4 o;
    o.x = f2bf(v.x * rs * wv.x); o.y = f2bf(v.y * rs * wv.y);
    o.z = f2bf(v.z * rs * wv.z); o.w = f2bf(v.w * rs * wv.w);
    ((ushort4*)sn)[(long)row * 256 + tid] = o;
    ushort4 r;
    r.x = f2bf(v.x); r.y = f2bf(v.y); r.z = f2bf(v.z); r.w = f2bf(v.w);
    ((ushort4*)slotsb)[(long)row * 256 + tid] = r;
  }
}

// ---------------- GEMM: C = alpha * A[M][K] @ W[N][K]^T (+bias) ----------------
// EPI: 0 = plain store; 2 = softmax over M(=64) -> bf16 attn + row partials.
// SPLIT: K-split batching. QGH: z=0 -> A/W cols[0,1024); z>0 -> A2/W2 slab.
// M12: blockIdx.y >= 16 switches W to W2 (combined A/C buffers).
template <int BM, int BN, int WR, int WC, typename CT, int EPI, int SPLIT, int QGH, int M12>
__global__ __launch_bounds__(WR * WC * 64) void gemm_bt(
    const unsigned short* __restrict__ A, const unsigned short* __restrict__ W,
    CT* __restrict__ C, int N, int Klen, int lda, int ldw,
    long sA, long sW, long sC, const float* __restrict__ bias,
    const float* __restrict__ bias2, float alpha, float* __restrict__ rs_part,
    const unsigned short* __restrict__ A2, const unsigned short* __restrict__ W2) {
  constexpr int BK = 64;
  constexpr int NT = WR * WC * 64;
  static_assert(NT == 256, "256 threads");
  constexpr int WSM = BM / WR, WSN = BN / WC;
  constexpr int MR = WSM / 16, NR = WSN / 16;
  constexpr int SEG_A = BM / 8, SEG_W = BN / 8;
  constexpr int PA = SEG_A / 4, PW = SEG_W / 4;
  static_assert(SEG_A % 4 == 0 && SEG_W % 4 == 0, "seg divisibility");
  __shared__ unsigned short As[BM * BK];
  __shared__ unsigned short Ws[BN * BK];
  const int tid = threadIdx.x, lane = tid & 63, wid = tid >> 6;
  const int wr = wid / WC, wc = wid % WC;
  const int tileN = blockIdx.x * BN, tileM = blockIdx.y * BM;
  int coff = 0;
  int zb = 0;
  if constexpr (QGH) {
    const int zz = blockIdx.z;
    if (zz > 0) {
      A = A2;
      W = W2 + (long)(zz - 1) * 1024 * ldw;
      bias = bias2 + (zz - 1) * 1024;
      coff = zz * 1024;
    }
  } else if constexpr (M12) {
    if (blockIdx.y >= 16) W = W2;
  } else {
    zb = blockIdx.z / SPLIT;
    const int zs = blockIdx.z % SPLIT;
    A += (long)zb * sA + (long)zs * Klen;
    W += (long)zb * sW + (long)zs * Klen;
    C += (long)blockIdx.z * sC;
  }
  const int srow = lane >> 3;
  const int scol = (lane & 7) * 8;
  f32x4 acc[MR][NR];
  #pragma unroll
  for (int i = 0; i < MR; i++)
    #pragma unroll
    for (int j = 0; j < NR; j++) acc[i][j] = (f32x4){0.f, 0.f, 0.f, 0.f};
  const int fr = lane & 15, fq = lane >> 4;

  for (int k0 = 0; k0 < Klen; k0 += BK) {
    #pragma unroll
    for (int p = 0; p < PA; p++) {
      int seg = wid * PA + p;
      gload16(A + (long)(tileM + seg * 8 + srow) * lda + k0 + scol, &As[seg * 512]);
    }
    #pragma unroll
    for (int p = 0; p < PW; p++) {
      int seg = wid * PW + p;
      gload16(W + (long)(tileN + seg * 8 + srow) * ldw + k0 + scol, &Ws[seg * 512]);
    }
    __syncthreads();
    #pragma unroll
    for (int kk = 0; kk < BK; kk += 32) {
      s16x8 af[MR], bf[NR];
      #pragma unroll
      for (int i = 0; i < MR; i++)
        af[i] = *(const s16x8*)(&As[(wr * WSM + i * 16 + fr) * BK + kk + fq * 8]);
      #pragma unroll
      for (int j = 0; j < NR; j++)
        bf[j] = *(const s16x8*)(&Ws[(wc * WSN + j * 16 + fr) * BK + kk + fq * 8]);
      #pragma unroll
      for (int i = 0; i < MR; i++)
        #pragma unroll
        for (int j = 0; j < NR; j++)
          acc[i][j] = __builtin_amdgcn_mfma_f32_16x16x32_bf16(af[i], bf[j], acc[i][j], 0, 0, 0);
    }
    __syncthreads();
  }

  if constexpr (EPI == 2) {
    static_assert(WR == 1 && BM == 64, "softmax epilogue needs full-M wave");
    #pragma unroll
    for (int i = 0; i < MR; i++)
      #pragma unroll
      for (int j = 0; j < NR; j++)
        #pragma unroll
        for (int q = 0; q < 4; q++) acc[i][j][q] *= alpha;
    float inv[NR];
    #pragma unroll
    for (int j = 0; j < NR; j++) {
      float mx = -1e30f;
      #pragma unroll
      for (int i = 0; i < MR; i++)
        #pragma unroll
        for (int q = 0; q < 4; q++) mx = fmaxf(mx, acc[i][j][q]);
      mx = fmaxf(mx, __shfl_xor(mx, 16, 64));
      mx = fmaxf(mx, __shfl_xor(mx, 32, 64));
      float sm = 0.f;
      #pragma unroll
      for (int i = 0; i < MR; i++)
        #pragma unroll
        for (int q = 0; q < 4; q++) {
          float e = __expf(acc[i][j][q] - mx);
          acc[i][j][q] = e;
          sm += e;
        }
      sm += __shfl_xor(sm, 16, 64);
      sm += __shfl_xor(sm, 32, 64);
      inv[j] = 1.f / sm;
    }
    float rp[MR][4];
    #pragma unroll
    for (int i = 0; i < MR; i++)
      #pragma unroll
      for (int q = 0; q < 4; q++) rp[i][q] = 0.f;
    unsigned short* Cs = (unsigned short*)C;
    #pragma unroll
    for (int i = 0; i < MR; i++)
      #pragma unroll
      for (int j = 0; j < NR; j++)
        #pragma unroll
        for (int q = 0; q < 4; q++) {
          float a = acc[i][j][q] * inv[j];
          rp[i][q] += a;
          Cs[(long)(i * 16 + fq * 4 + q) * N + tileN + wc * WSN + j * 16 + fr] = f2bf(a);
        }
    #pragma unroll
    for (int off = 1; off <= 8; off <<= 1)
      #pragma unroll
      for (int i = 0; i < MR; i++)
        #pragma unroll
        for (int q = 0; q < 4; q++) rp[i][q] += __shfl_xor(rp[i][q], off, 64);
    if (fr == 0) {
      const int rld = gridDim.x * WC;
      #pragma unroll
      for (int i = 0; i < MR; i++)
        #pragma unroll
        for (int q = 0; q < 4; q++)
          rs_part[((long)zb * 64 + i * 16 + fq * 4 + q) * rld + blockIdx.x * WC + wc] = rp[i][q];
    }
    return;
  }

  #pragma unroll
  for (int i = 0; i < MR; i++) {
    const int mbase = tileM + wr * WSM + i * 16 + fq * 4;
    #pragma unroll
    for (int j = 0; j < NR; j++) {
      const int n = tileN + wc * WSN + j * 16 + fr;
      const float bv = bias ? bias[n] : 0.f;
      #pragma unroll
      for (int q = 0; q < 4; q++) {
        float v = acc[i][j][q] * alpha + bv;
        if constexpr (sizeof(CT) == 2)
          C[(long)(mbase + q) * N + coff + n] = f2bf(v);
        else
          C[(long)(mbase + q) * N + coff + n] = v;
      }
    }
  }
}

// ---- reduce 4 bf16 K-splits; in-block rowsum of rs_part (256 partials) -> rowinv; scale; bf16 ----
__global__ __launch_bounds__(256) void upd_reduce_k(const unsigned short* __restrict__ part,
                                                    const float* __restrict__ rs_part,
                                                    unsigned short* __restrict__ out) {
  const int row = blockIdx.x;  // b*64 + k
  const int tid = threadIdx.x;
  float s = rs_part[(long)row * 256 + tid];
  #pragma unroll
  for (int off = 32; off; off >>= 1) s += __shfl_xor(s, off, 64);
  __shared__ float sb[4];
  if ((tid & 63) == 0) sb[tid >> 6] = s;
  __syncthreads();
  const float inv = 1.f / (sb[0] + sb[1] + sb[2] + sb[3] + 1e-6f);
  const unsigned short* base =
      part + (long)(row >> 6) * 4 * 65536 + (long)(row & 63) * 1024 + tid * 4;
  float ax = 0.f, ay = 0.f, az = 0.f, aw = 0.f;
  #pragma unroll
  for (int sp = 0; sp < 4; sp++) {
    ushort4 v = *(const ushort4*)(base + (long)sp * 65536);
    ax += bf2f(v.x); ay += bf2f(v.y); az += bf2f(v.z); aw += bf2f(v.w);
  }
  ushort4 o;
  o.x = f2bf(ax * inv); o.y = f2bf(ay * inv);
  o.z = f2bf(az * inv); o.w = f2bf(aw * inv);
  ((ushort4*)out)[(long)row * 256 + tid] = o;
}

// ---- GRU combine (bf16 gi / gh-in-qgh) + fused rmsnorm of the new slots ----
__global__ __launch_bounds__(256) void gru_k(const unsigned short* __restrict__ gi,
                                             const unsigned short* __restrict__ qgh,
                                             const float* __restrict__ h,
                                             const float* __restrict__ snw,
                                             float* __restrict__ out,
                                             unsigned short* __restrict__ out_bf,
                                             unsigned short* __restrict__ sn_out) {
  const int r = blockIdx.x;
  const int tid = threadIdx.x;
  const int c = tid * 4;
  const unsigned short* gip = gi + (long)r * 3072;
  const unsigned short* ghp = qgh + (long)r * 4096 + 1024;
  ushort4 iru = *(const ushort4*)(gip + c);
  ushort4 izu = *(const ushort4*)(gip + 1024 + c);
  ushort4 inu = *(const ushort4*)(gip + 2048 + c);
  ushort4 hru = *(const ushort4*)(ghp + c);
  ushort4 hzu = *(const ushort4*)(ghp + 1024 + c);
  ushort4 hnu = *(const ushort4*)(ghp + 2048 + c);
  float4 hv = *(const float4*)(h + (long)r * 1024 + c);
  float4 o;
  { float rr = sigm(bf2f(iru.x) + bf2f(hru.x)), zz = sigm(bf2f(izu.x) + bf2f(hzu.x));
    float nn = tanhf(bf2f(inu.x) + rr * bf2f(hnu.x)); o.x = (1.f - zz) * nn + zz * hv.x; }
  { float rr = sigm(bf2f(iru.y) + bf2f(hru.y)), zz = sigm(bf2f(izu.y) + bf2f(hzu.y));
    float nn = tanhf(bf2f(inu.y) + rr * bf2f(hnu.y)); o.y = (1.f - zz) * nn + zz * hv.y; }
  { float rr = sigm(bf2f(iru.z) + bf2f(hru.z)), zz = sigm(bf2f(izu.z) + bf2f(hzu.z));
    float nn = tanhf(bf2f(inu.z) + rr * bf2f(hnu.z)); o.z = (1.f - zz) * nn + zz * hv.z; }
  { float rr = sigm(bf2f(iru.w) + bf2f(hru.w)), zz = sigm(bf2f(izu.w) + bf2f(hzu.w));
    float nn = tanhf(bf2f(inu.w) + rr * bf2f(hnu.w)); o.w = (1.f - zz) * nn + zz * hv.w; }
  *(float4*)(out + (long)r * 1024 + c) = o;
  ushort4 ob;
  ob.x = f2bf(o.x); ob.y = f2bf(o.y); ob.z = f2bf(o.z); ob.w = f2bf(o.w);
  *(ushort4*)(out_bf + (long)r * 1024 + c) = ob;
  float ss = o.x * o.x + o.y * o.y + o.z * o.z + o.w * o.w;
  #pragma unroll
  for (int off = 32; off; off >>= 1) ss += __shfl_xor(ss, off, 64);
  __shared__ float sb[4];
  if ((tid & 63) == 0) sb[tid >> 6] = ss;
  __syncthreads();
  const float tot = sb[0] + sb[1] + sb[2] + sb[3];
  const float rs = rsqrtf(tot * (1.0f / 1024.0f) + 1e-6f);
  float4 wv = *(const float4*)(snw + c);
  ushort4 so;
  so.x = f2bf(o.x * rs * wv.x); so.y = f2bf(o.y * rs * wv.y);
  so.z = f2bf(o.z * rs * wv.z); so.w = f2bf(o.w * rs * wv.w);
  *(ushort4*)(sn_out + (long)r * 1024 + c) = so;
}

extern "C" void kernel_launch(void* const* d_in, const int* in_sizes, int n_in,
                              void* d_out, int out_size, void* d_ws, size_t ws_size,
                              hipStream_t stream) {
  const float* slots_in = (const float*)d_in[0];
  const float* P        = (const float*)d_in[1];
  const float* Wq       = (const float*)d_in[2];
  const float* Wk       = (const float*)d_in[3];
  const float* Wv       = (const float*)d_in[4];
  const float* wi       = (const float*)d_in[5];
  const float* wh       = (const float*)d_in[6];
  const float* bi       = (const float*)d_in[7];
  const float* bh       = (const float*)d_in[8];
  const float* snw      = (const float*)d_in[9];
  const float* inw      = (const float*)d_in[10];

  const size_t MB = 1024ull * 1024ull;
  char* ws = (char*)d_ws;
  unsigned short* Pn    = (unsigned short*)(ws + 0);        // 64MB [b][m][d] bf16 (persists)
  unsigned short* Pnt   = (unsigned short*)(ws + 64 * MB);  // 64MB [b][d][m] bf16 (persists)
  char* S               = ws + 128 * MB;                    // iteration region
  unsigned short* sn    = (unsigned short*)(S);             // 1MB
  unsigned short* qgh   = (unsigned short*)(S + 1 * MB);    // 4MB [512][4096]: qm | gh
  unsigned short* attnb = (unsigned short*)(S + 5 * MB);    // 4MB
  unsigned short* updb  = (unsigned short*)(S + 9 * MB);    // 1MB (t * rowinv, bf16)
  unsigned short* slotsb= (unsigned short*)(S + 10 * MB);   // 1MB
  unsigned short* gi_b  = (unsigned short*)(S + 11 * MB);   // 3MB [512][3072]
  unsigned short* Cpart = (unsigned short*)(S + 14 * MB);   // 4MB bf16 [32][64][1024]
  float* rs_part        = (float*)(S + 22 * MB);            // 512KB [512][256]
  unsigned short* wqt   = (unsigned short*)(S + 23 * MB);   // 2MB (Wq^T bf16)
  unsigned short* wvt   = (unsigned short*)(S + 25 * MB);   // 2MB (Wv^T bf16)
  unsigned short* wh_b  = (unsigned short*)(S + 27 * MB);   // 6MB
  unsigned short* wkt   = (unsigned short*)(S + 33 * MB);   // 2MB } combined A4 [4096][1024]
  unsigned short* wi_b  = (unsigned short*)(S + 35 * MB);   // 6MB }
  unsigned short* m1_b  = (unsigned short*)(S + 41 * MB);   // 2MB } combined C4 [4096][1024]
  unsigned short* m2_b  = (unsigned short*)(S + 43 * MB);   // 6MB }
  float* slots          = (float*)(ws + 196 * MB);          // 2MB

  // ---- prologue (4 dispatches) ----
  prep_k<<<4352, 256, 0, stream>>>(Wq, Wk, Wv, wi, wh, slots_in, snw,
                                   wqt, wkt, wvt, wi_b, wh_b, sn, slotsb);
  rmsnorm_k<<<32768, 256, 0, stream>>>(P, inw, Pn);
  tp_k<<<8192, 256, 0, stream>>>(Pn, Pnt);
  // merged M1 = Wk^T @ Wq (y<16) and M2 = wi @ Wv (y>=16); combined A/C buffers
  gemm_bt<64, 64, 2, 2, unsigned short, 0, 1, 0, 1>
      <<<dim3(16, 64, 1), 256, 0, stream>>>(wkt, wqt, m1_b, 1024, 1024, 1024, 1024,
                                            0, 0, 0, nullptr, nullptr, 1.f, nullptr,
                                            nullptr, wvt);

  // ---- 3 iterations (6 dispatches each) ----
  for (int it = 0; it < 3; ++it) {
    // merged qm+gh: z=0 -> qm = sn@M1^T; z=1..3 -> gh slab = slotsb@wh^T+bh
    gemm_bt<64, 64, 2, 2, unsigned short, 0, 1, 1, 0>
        <<<dim3(16, 8, 4), 256, 0, stream>>>(sn, m1_b, qgh, 4096, 1024, 1024, 1024,
                                             0, 0, 0, nullptr, bh, 1.f, nullptr,
                                             slotsb, wh_b);
    // attn[b][k][m] = softmax_k((qm_b @ Pn_b^T)/32) + row partials (BN=64, 512 blocks)
    gemm_bt<64, 64, 1, 4, unsigned short, 2, 1, 0, 0>
        <<<dim3(64, 1, 8), 256, 0, stream>>>(qgh, Pn, attnb, 4096, 1024, 4096, 1024,
                                             64L * 4096, 4096L * 1024, 64L * 4096,
                                             nullptr, nullptr, 0.03125f, rs_part,
                                             nullptr, nullptr);
    // t partials (bf16): attn_b @ Pnt_b^T, K=4096 split 4x1024 (512 blocks)
    gemm_bt<64, 64, 2, 2, unsigned short, 0, 4, 0, 0>
        <<<dim3(16, 1, 32), 256, 0, stream>>>(attnb, Pnt, Cpart, 1024, 1024, 4096, 4096,
                                              64L * 4096, 1024L * 4096, 64L * 1024,
                                              nullptr, nullptr, 1.f, nullptr,
                                              nullptr, nullptr);
    upd_reduce_k<<<512, 256, 0, stream>>>(Cpart, rs_part, updb);
    // gi = (t*rowinv) @ M2^T + bi -> bf16 [512][3072]
    gemm_bt<64, 64, 2, 2, unsigned short, 0, 1, 0, 0>
        <<<dim3(48, 8, 1), 256, 0, stream>>>(updb, m2_b, gi_b, 3072, 1024, 1024, 1024,
                                             0, 0, 0, bi, nullptr, 1.f, nullptr,
                                             nullptr, nullptr);
    const float* hsrc = (it == 0) ? slots_in : slots;
    float* dst = (it == 2) ? (float*)d_out : slots;
    gru_k<<<512, 256, 0, stream>>>(gi_b, qgh, hsrc, snw, dst, slotsb, sn);
  }
}